// Round 1
// 664.865 us; speedup vs baseline: 1.0699x; 1.0699x over previous
//
#include <hip/hip_runtime.h>

#define N_IND 100000
#define N_COM 100000
#define N_TRU 100000
#define NTOT  300000
#define NEDGE 4800000
#define HDIM  64
#define CHUNK 8192
#define NCHUNKS 586   // ceil(NEDGE/CHUNK)
#define NCB 293       // ceil(NTOT/1024) coarse buckets of 1024 nodes
#define PADW 33       // 32 cols + 1 pad (encoder epilogue)
#define NTILES 18750  // NTOT / 16 exactly
#define CMB_BLOCKS 1184

typedef float v4f __attribute__((ext_vector_type(4)));
typedef unsigned short v4u __attribute__((ext_vector_type(4)));
typedef _Float16 v8h __attribute__((ext_vector_type(8)));

static __device__ __forceinline__ float elem4(const float4 v, int j) {
  return j == 0 ? v.x : j == 1 ? v.y : j == 2 ? v.z : v.w;
}

// fp32 <-> fp16 (RTN via v_cvt)
static __device__ __forceinline__ unsigned short f2h(float f) {
  _Float16 h = (_Float16)f;
  return __builtin_bit_cast(unsigned short, h);
}
static __device__ __forceinline__ float h2f(unsigned short u) {
  return (float)__builtin_bit_cast(_Float16, u);
}

// Coalesced fp16 epilogue for encoder (256 rows, 2 stages of 32 cols).
static __device__ __forceinline__ void store_rows_f16(
    unsigned short* __restrict__ out, float* __restrict__ st, const float* acc,
    int node0, int rows, int tid, bool active) {
#pragma unroll
  for (int stage = 0; stage < 2; ++stage) {
    __syncthreads();
    if (active) {
#pragma unroll
      for (int j = 0; j < 32; ++j) st[tid * PADW + j] = acc[stage * 32 + j];
    }
    __syncthreads();
#pragma unroll
    for (int it = 0; it < 8; ++it) {
      int e = it * 256 + tid;
      int r = e >> 3;
      int c = (e & 7) * 4;
      if (r < rows) {
        v4u o;
        o.x = f2h(st[r * PADW + c + 0]);
        o.y = f2h(st[r * PADW + c + 1]);
        o.z = f2h(st[r * PADW + c + 2]);
        o.w = f2h(st[r * PADW + c + 3]);
        *(v4u*)(out + (size_t)(node0 + r) * HDIM + stage * 32 + c) = o;
      }
    }
  }
}

// ---------------- encoder: xh[base+n] = fp16(x[n] @ W + b) ----------------
template <int K>
__global__ __launch_bounds__(256, 2) void encode_kernel(
    const float* __restrict__ xin, const float* __restrict__ W,
    const float* __restrict__ b, unsigned short* __restrict__ xhout, int n, int base) {
  __shared__ float st[256 * PADW];
  int tid = threadIdx.x;
  int node0 = blockIdx.x * 256;
  int node = node0 + tid;
  bool active = node < n;
  int rows = min(256, n - node0);
  float acc[HDIM];
  if (active) {
    float4 row[K / 4];
    const float4* xv = (const float4*)(xin + (size_t)node * K);
#pragma unroll
    for (int i = 0; i < K / 4; ++i) row[i] = xv[i];
#pragma unroll
    for (int f = 0; f < HDIM; ++f) acc[f] = b[f];  // uniform -> s_load
#pragma unroll
    for (int k4 = 0; k4 < K / 4; ++k4) {
#pragma unroll
      for (int j = 0; j < 4; ++j) {
        float xs = elem4(row[k4], j);
        int k = k4 * 4 + j;
#pragma unroll
        for (int f = 0; f < HDIM; ++f) acc[f] += xs * W[k * HDIM + f];
      }
    }
  }
  store_rows_f16(xhout + (size_t)base * HDIM, st, acc, node0, rows, tid, active);
}

// ---------------- weight prep: fp32 -> fp16, swizzled to B-fragment order ----------------
// frag layout per 64x64 matrix: out[ts*512 + l*8 + j] = W[s*32 + (l>>4)*8 + j][t*16 + (l&15)]
// where ts = t*2+s. A v8h load at index (ts*64 + lane) yields lane's B fragment.
__global__ __launch_bounds__(256) void prep_weights_kernel(
    const float* __restrict__ W1l, const float* __restrict__ W1r,
    const float* __restrict__ W2l, const float* __restrict__ W2r,
    unsigned short* __restrict__ out) {
  const float* Ws[4] = {W1l, W1r, W2l, W2r};
  int tid = threadIdx.x;
  for (int m = 0; m < 4; ++m) {
    const float* W = Ws[m];
    unsigned short* o = out + m * 4096;
    for (int idx = tid; idx < 4096; idx += 256) {
      int j = idx & 7;
      int l = (idx >> 3) & 63;
      int ts = idx >> 9;
      int t = ts >> 1, s = ts & 1;
      int k = s * 32 + (l >> 4) * 8 + j;
      int n = t * 16 + (l & 15);
      o[idx] = f2h(W[k * HDIM + n]);
    }
  }
}

// ---------------- coarse histogram: LDS-aggregated, 293 bins ----------------
__global__ __launch_bounds__(256) void coarse_hist_kernel(const int* __restrict__ dst,
                                                          int* __restrict__ chist, int e) {
  __shared__ int h[NCB];
  int tid = threadIdx.x;
  int start = blockIdx.x * CHUNK;
  int len = min(CHUNK, e - start);
  for (int i = tid; i < NCB; i += 256) h[i] = 0;
  __syncthreads();
  for (int i = tid; i < len; i += 256) atomicAdd(&h[dst[start + i] >> 10], 1);
  __syncthreads();
  for (int b = tid; b < NCB; b += 256) {
    int c = h[b];
    if (c > 0) atomicAdd(&chist[b], c);
  }
}

// ---------------- exclusive scan of 293 coarse counts ----------------
__global__ __launch_bounds__(512) void coarse_scan_kernel(const int* __restrict__ chist,
                                                          int* __restrict__ cbase,
                                                          int* __restrict__ ccur) {
  __shared__ int sv[512];
  int t = threadIdx.x;
  sv[t] = (t < NCB) ? chist[t] : 0;
  __syncthreads();
  for (int o = 1; o < 512; o <<= 1) {
    int y = (t >= o) ? sv[t - o] : 0;
    __syncthreads();
    sv[t] += y;
    __syncthreads();
  }
  if (t < NCB) {
    int ex = (t == 0) ? 0 : sv[t - 1];
    cbase[t] = ex;
    ccur[t] = ex;
  }
}

// ---------------- coarse scatter: LDS-staged local sort, coalesced run writes ----------
// Old version wrote packed[lbase[b]+r] in random temporal order -> ~4.6x write
// amplification (WRITE_SIZE 89 MB vs 19.2 ideal), latency-bound on store transactions.
// New version counting-sorts the chunk in LDS first, then writes each bucket run as a
// dense sequential sweep (consecutive threads -> consecutive addresses within a run).
__global__ __launch_bounds__(256) void coarse_scatter_kernel(
    const int* __restrict__ src, const int* __restrict__ dst,
    int* __restrict__ ccur, unsigned* __restrict__ packed, int e) {
  __shared__ int h[NCB];        // per-bucket counts, then rank counters
  __shared__ int gofs[NCB];     // lbase[b] - lofs[b]  (global offset per slot)
  __shared__ int sv[512];       // Hillis-Steele scan buffer
  __shared__ unsigned vals[CHUNK];        // locally sorted packed values
  __shared__ unsigned short bid[CHUNK];   // bucket id per slot
  int tid = threadIdx.x;
  int start = blockIdx.x * CHUNK;
  int len = min(CHUNK, e - start);

  for (int i = tid; i < NCB; i += 256) h[i] = 0;
  __syncthreads();

  // Phase A: histogram; keep dst values in registers for phase C.
  int dreg[CHUNK / 256];
#pragma unroll
  for (int k = 0; k < CHUNK / 256; ++k) {
    int i = k * 256 + tid;
    dreg[k] = (i < len) ? dst[start + i] : -1;
    if (i < len) atomicAdd(&h[dreg[k] >> 10], 1);
  }
  __syncthreads();

  // Phase B: block-local inclusive scan of 293 counts (512-wide Hillis-Steele,
  // 256 threads x 2 slots). Then exclusive base lofs, reserve global run, set ranks.
  sv[tid] = (tid < NCB) ? h[tid] : 0;
  sv[tid + 256] = (tid + 256 < NCB) ? h[tid + 256] : 0;
  __syncthreads();
  for (int o = 1; o < 512; o <<= 1) {
    int y0 = (tid >= o) ? sv[tid - o] : 0;
    int y1 = sv[tid + 256 - o];  // tid+256 >= o always (o <= 256)
    __syncthreads();
    sv[tid] += y0;
    sv[tid + 256] += y1;
    __syncthreads();
  }
  for (int b = tid; b < NCB; b += 256) {
    int c = h[b];
    int lo = (b == 0) ? 0 : sv[b - 1];
    int gb = (c > 0) ? atomicAdd(&ccur[b], c) : 0;  // reserve contiguous run
    gofs[b] = gb - lo;
    h[b] = lo;  // reuse as rank counter
  }
  __syncthreads();

  // Phase C: scatter into LDS in locally-sorted order.
#pragma unroll
  for (int k = 0; k < CHUNK / 256; ++k) {
    int i = k * 256 + tid;
    if (i < len) {
      int d = dreg[k];
      int s = src[start + i];
      int b = d >> 10;
      int slot = atomicAdd(&h[b], 1);
      vals[slot] = ((unsigned)s << 10) | (unsigned)(d & 1023);
      bid[slot] = (unsigned short)b;
    }
  }
  __syncthreads();

  // Phase D: coalesced sweep; within each bucket run, consecutive slots map to
  // consecutive global addresses.
  for (int i = tid; i < len; i += 256) {
    int b = bid[i];
    packed[gofs[b] + i] = vals[i];
  }
}

// ---------------- per-coarse-bucket counting sort -> node-grouped CSR ----------------
__global__ __launch_bounds__(256) void sort_coarse_kernel(
    const unsigned* __restrict__ packed, const int* __restrict__ cbase,
    const int* __restrict__ chist, int* __restrict__ eidx,
    int* __restrict__ nodeoff, int* __restrict__ deg) {
  __shared__ int cnts[1024];
  __shared__ int cur[1024];
  __shared__ int part[256];
  int cb = blockIdx.x;
  int tid = threadIdx.x;
  for (int i = tid; i < 1024; i += 256) cnts[i] = 0;
  __syncthreads();
  int base = cbase[cb];
  int cnt = chist[cb];
  for (int i = tid; i < cnt; i += 256)
    atomicAdd(&cnts[packed[base + i] & 1023u], 1);
  __syncthreads();
  int c0 = cnts[4 * tid + 0], c1 = cnts[4 * tid + 1];
  int c2 = cnts[4 * tid + 2], c3 = cnts[4 * tid + 3];
  part[tid] = c0 + c1 + c2 + c3;
  __syncthreads();
  for (int o = 1; o < 256; o <<= 1) {
    int y = (tid >= o) ? part[tid - o] : 0;
    __syncthreads();
    part[tid] += y;
    __syncthreads();
  }
  int pre = (tid == 0) ? 0 : part[tid - 1];
  int e0 = pre, e1 = e0 + c0, e2 = e1 + c1, e3 = e2 + c2;
  cur[4 * tid + 0] = e0; cur[4 * tid + 1] = e1;
  cur[4 * tid + 2] = e2; cur[4 * tid + 3] = e3;
  int nodebase = (cb << 10) + 4 * tid;
  if (nodebase + 0 < NTOT) { deg[nodebase + 0] = c0; nodeoff[nodebase + 0] = base + e0; }
  if (nodebase + 1 < NTOT) { deg[nodebase + 1] = c1; nodeoff[nodebase + 1] = base + e1; }
  if (nodebase + 2 < NTOT) { deg[nodebase + 2] = c2; nodeoff[nodebase + 2] = base + e2; }
  if (nodebase + 3 < NTOT) { deg[nodebase + 3] = c3; nodeoff[nodebase + 3] = base + e3; }
  __syncthreads();
  for (int i = tid; i < cnt; i += 256) {
    unsigned pr = packed[base + i];
    int dl = (int)(pr & 1023u);
    int r = atomicAdd(&cur[dl], 1);
    eidx[base + r] = (int)(pr >> 10);  // 64 KB region exclusive to this block
  }
}

// ---------------- mean aggregation: fp16 in, fp16 out, 16 lanes/node ----------------
__global__ __launch_bounds__(256) void aggregate_kernel(
    const unsigned short* __restrict__ xh, const int* __restrict__ off,
    const int* __restrict__ deg, const int* __restrict__ eidx,
    unsigned short* __restrict__ meanh, int n) {
  int tid = blockIdx.x * 256 + threadIdx.x;
  int node = tid >> 4;
  int lane = tid & 15;
  if (node >= n) return;
  int start = off[node];
  int d = deg[node];
  const v4u* xv = (const v4u*)xh;   // row = 16 x v4u (128 B)
  float4 a0 = make_float4(0.f, 0.f, 0.f, 0.f);
  float4 a1 = make_float4(0.f, 0.f, 0.f, 0.f);
  float4 a2 = make_float4(0.f, 0.f, 0.f, 0.f);
  float4 a3 = make_float4(0.f, 0.f, 0.f, 0.f);
  int i = 0;
  for (; i + 4 <= d; i += 4) {
    int s0 = eidx[start + i + 0];
    int s1 = eidx[start + i + 1];
    int s2 = eidx[start + i + 2];
    int s3 = eidx[start + i + 3];
    v4u v0 = xv[(size_t)s0 * 16 + lane];
    v4u v1 = xv[(size_t)s1 * 16 + lane];
    v4u v2 = xv[(size_t)s2 * 16 + lane];
    v4u v3 = xv[(size_t)s3 * 16 + lane];
    a0.x += h2f(v0.x); a0.y += h2f(v0.y); a0.z += h2f(v0.z); a0.w += h2f(v0.w);
    a1.x += h2f(v1.x); a1.y += h2f(v1.y); a1.z += h2f(v1.z); a1.w += h2f(v1.w);
    a2.x += h2f(v2.x); a2.y += h2f(v2.y); a2.z += h2f(v2.z); a2.w += h2f(v2.w);
    a3.x += h2f(v3.x); a3.y += h2f(v3.y); a3.z += h2f(v3.z); a3.w += h2f(v3.w);
  }
  for (; i < d; ++i) {
    int s = eidx[start + i];
    v4u v = xv[(size_t)s * 16 + lane];
    a0.x += h2f(v.x); a0.y += h2f(v.y); a0.z += h2f(v.z); a0.w += h2f(v.w);
  }
  float inv = 1.0f / (float)(d > 0 ? d : 1);
  v4u o;
  o.x = f2h((a0.x + a1.x + a2.x + a3.x) * inv);
  o.y = f2h((a0.y + a1.y + a2.y + a3.y) * inv);
  o.z = f2h((a0.z + a1.z + a2.z + a3.z) * inv);
  o.w = f2h((a0.w + a1.w + a2.w + a3.w) * inv);
  __builtin_nontemporal_store(o, (v4u*)meanh + (size_t)node * 16 + lane);
}

// ---------------- combine via MFMA: relu(mean@Wl + x@Wr + b) ----------------
// One wave per 16-node M-tile (grid-stride). D[16x64] = A_mean[16x64]@Wl + A_x[16x64]@Wr + b.
// mfma_f32_16x16x32_f16: A[m=lane&15][k=quad*8+j], B[k=quad*8+j][n=lane&15] (pre-swizzled),
// C/D: col=lane&15, row=quad*4+reg. Epilogue: per-wave LDS staging (no block barrier —
// waves have different trip counts), line-complete stores.
__global__ __launch_bounds__(256, 4) void combine_mfma_kernel(
    const unsigned short* __restrict__ meanh, const unsigned short* __restrict__ xh,
    const unsigned short* __restrict__ wfrag,  // [2 matrices][8 frags][64 lanes][8 halfs]
    const float* __restrict__ bb, float* __restrict__ outf,
    unsigned short* __restrict__ outh) {
  __shared__ float st[4][16 * 68 + 8];
  int tid = threadIdx.x;
  int wid = tid >> 6;
  int lane = tid & 63;
  int mlo = lane & 15;
  int quad = lane >> 4;
  const v8h* wf = (const v8h*)wfrag;
  v8h BL[8], BR[8];
#pragma unroll
  for (int i = 0; i < 8; ++i) BL[i] = wf[i * 64 + lane];
#pragma unroll
  for (int i = 0; i < 8; ++i) BR[i] = wf[512 + i * 64 + lane];
  float bias[4];
#pragma unroll
  for (int t = 0; t < 4; ++t) bias[t] = bb[t * 16 + mlo];
  float* stw = st[wid];
  int gw = blockIdx.x * 4 + wid;
  int nw = CMB_BLOCKS * 4;
  for (int tile = gw; tile < NTILES; tile += nw) {
    int node0 = tile * 16;
    const _Float16* mrow = (const _Float16*)meanh + (size_t)(node0 + mlo) * HDIM + quad * 8;
    const _Float16* xrow = (const _Float16*)xh + (size_t)(node0 + mlo) * HDIM + quad * 8;
    v8h Am0 = *(const v8h*)(mrow);
    v8h Am1 = *(const v8h*)(mrow + 32);
    v8h Ax0 = *(const v8h*)(xrow);
    v8h Ax1 = *(const v8h*)(xrow + 32);
#pragma unroll
    for (int t = 0; t < 4; ++t) {
      v4f acc = {bias[t], bias[t], bias[t], bias[t]};
      acc = __builtin_amdgcn_mfma_f32_16x16x32_f16(Am0, BL[t * 2 + 0], acc, 0, 0, 0);
      acc = __builtin_amdgcn_mfma_f32_16x16x32_f16(Am1, BL[t * 2 + 1], acc, 0, 0, 0);
      acc = __builtin_amdgcn_mfma_f32_16x16x32_f16(Ax0, BR[t * 2 + 0], acc, 0, 0, 0);
      acc = __builtin_amdgcn_mfma_f32_16x16x32_f16(Ax1, BR[t * 2 + 1], acc, 0, 0, 0);
#pragma unroll
      for (int r = 0; r < 4; ++r)
        stw[(quad * 4 + r) * 68 + t * 16 + mlo] = fmaxf(acc[r], 0.f);
    }
    // wave-local LDS RAW: compiler inserts lgkmcnt waits; no barrier (per-wave region)
    int rr = lane >> 2;
    int c0 = (lane & 3) * 16;
    const float* ap = &stw[rr * 68 + c0];
    if (outh) {
      unsigned short* orow = outh + (size_t)(node0 + rr) * HDIM + c0;
#pragma unroll
      for (int g = 0; g < 4; ++g) {
        v4u o;
        o.x = f2h(ap[g * 4 + 0]); o.y = f2h(ap[g * 4 + 1]);
        o.z = f2h(ap[g * 4 + 2]); o.w = f2h(ap[g * 4 + 3]);
        *(v4u*)(orow + g * 4) = o;
      }
    } else {
      float* orow = outf + (size_t)(node0 + rr) * HDIM + c0;
#pragma unroll
      for (int g = 0; g < 4; ++g) {
        float4 o;
        o.x = ap[g * 4 + 0]; o.y = ap[g * 4 + 1];
        o.z = ap[g * 4 + 2]; o.w = ap[g * 4 + 3];
        *(float4*)(orow + g * 4) = o;
      }
    }
  }
}

// ---------------- classifier: out = relu(x@Wc1+bc1)@Wc2 + bc2  (fp32 input) ----------------
__global__ __launch_bounds__(256, 2) void classifier_kernel(
    const float* __restrict__ x, const float* __restrict__ W1, const float* __restrict__ b1,
    const float* __restrict__ W2, const float* __restrict__ b2,
    float* __restrict__ out, int n) {
  int node = blockIdx.x * 256 + threadIdx.x;
  if (node >= n) return;
  float4 row[16];
  const float4* xv = (const float4*)(x + (size_t)node * HDIM);
#pragma unroll
  for (int i = 0; i < 16; ++i) row[i] = xv[i];
  float h[32];
#pragma unroll
  for (int f = 0; f < 32; ++f) h[f] = b1[f];
#pragma unroll
  for (int k4 = 0; k4 < 16; ++k4) {
#pragma unroll
    for (int j = 0; j < 4; ++j) {
      float xs = elem4(row[k4], j);
      int k = k4 * 4 + j;
#pragma unroll
      for (int f = 0; f < 32; ++f) h[f] += xs * W1[k * 32 + f];
    }
  }
  float o0 = b2[0], o1 = b2[1];
#pragma unroll
  for (int f = 0; f < 32; ++f) {
    float hv = fmaxf(h[f], 0.f);
    o0 += hv * W2[f * 2 + 0];
    o1 += hv * W2[f * 2 + 1];
  }
  float2 o;
  o.x = o0; o.y = o1;
  *(float2*)(out + (size_t)node * 2) = o;
}

extern "C" void kernel_launch(void* const* d_in, const int* in_sizes, int n_in,
                              void* d_out, int out_size, void* d_ws, size_t ws_size,
                              hipStream_t stream) {
  const float* x_ind = (const float*)d_in[0];
  const float* x_com = (const float*)d_in[1];
  const float* x_tru = (const float*)d_in[2];
  const int*   ei    = (const int*)d_in[3];
  const float* W_ind = (const float*)d_in[4];
  const float* b_ind = (const float*)d_in[5];
  const float* W_com = (const float*)d_in[6];
  const float* b_com = (const float*)d_in[7];
  const float* W_tru = (const float*)d_in[8];
  const float* b_tru = (const float*)d_in[9];
  const float* W1l = (const float*)d_in[10];
  const float* W1r = (const float*)d_in[11];
  const float* b1  = (const float*)d_in[12];
  const float* W2l = (const float*)d_in[13];
  const float* W2r = (const float*)d_in[14];
  const float* b2  = (const float*)d_in[15];
  const float* Wc1 = (const float*)d_in[16];
  const float* bc1 = (const float*)d_in[17];
  const float* Wc2 = (const float*)d_in[18];
  const float* bc2 = (const float*)d_in[19];

  const int* srcp = ei;           // edge_index[0]
  const int* dstp = ei + NEDGE;   // edge_index[1]

  // workspace layout (~212 MB; round-1 proved >=252 MB available)
  size_t fcount = (size_t)NTOT * HDIM;
  float* xf = (float*)d_ws;                        // fp32 final features (76.8 MB)
  unsigned* packed = (unsigned*)xf;                // ALIAS: dead before xf written
  unsigned short* xh0 = (unsigned short*)(xf + fcount);   // fp16 layer-0 features
  unsigned short* xh1 = xh0 + fcount;                     // fp16 layer-1 features
  unsigned short* mnh = xh1 + fcount;                     // fp16 mean (stream)
  int* eidx    = (int*)(mnh + fcount);
  int* nodeoff = eidx + NEDGE;
  int* deg     = nodeoff + NTOT;
  int* chist   = deg + NTOT;
  int* cbase   = chist + NCB;
  int* ccur    = cbase + NCB;
  // 16B-aligned weight-fragment area (4 matrices x 4096 halfs = 32 KB)
  unsigned short* wfrag = (unsigned short*)((((size_t)(ccur + NCB)) + 15) & ~(size_t)15);
  size_t needed = (size_t)((char*)(wfrag + 4 * 4096) - (char*)d_ws) + 64;
  if (ws_size < needed) return;  // would corrupt; fail visibly instead

  (void)hipMemsetAsync(chist, 0, (size_t)NCB * sizeof(int), stream);

  // weight prep (fp16 + fragment swizzle), independent of everything else
  prep_weights_kernel<<<1, 256, 0, stream>>>(W1l, W1r, W2l, W2r, wfrag);

  // encoders (write fp16 xh0; independent of edge pipeline)
  encode_kernel<32><<<(N_IND + 255) / 256, 256, 0, stream>>>(x_ind, W_ind, b_ind, xh0, N_IND, 0);
  encode_kernel<48><<<(N_COM + 255) / 256, 256, 0, stream>>>(x_com, W_com, b_com, xh0, N_COM, N_IND);
  encode_kernel<24><<<(N_TRU + 255) / 256, 256, 0, stream>>>(x_tru, W_tru, b_tru, xh0, N_TRU, N_IND + N_COM);

  // coarse partition -> per-coarse-bucket counting sort -> node-grouped CSR
  coarse_hist_kernel<<<NCHUNKS, 256, 0, stream>>>(dstp, chist, NEDGE);
  coarse_scan_kernel<<<1, 512, 0, stream>>>(chist, cbase, ccur);
  coarse_scatter_kernel<<<NCHUNKS, 256, 0, stream>>>(srcp, dstp, ccur, packed, NEDGE);
  sort_coarse_kernel<<<NCB, 256, 0, stream>>>(packed, cbase, chist, eidx, nodeoff, deg);

  // SAGE layer 1: aggregate fp16 -> fp16 mean; MFMA combine -> fp16 x1
  aggregate_kernel<<<(NTOT * 16 + 255) / 256, 256, 0, stream>>>(xh0, nodeoff, deg, eidx, mnh, NTOT);
  combine_mfma_kernel<<<CMB_BLOCKS, 256, 0, stream>>>(mnh, xh0, wfrag, b1, nullptr, xh1);

  // SAGE layer 2: aggregate fp16 -> fp16 mean; MFMA combine -> fp32 xf
  aggregate_kernel<<<(NTOT * 16 + 255) / 256, 256, 0, stream>>>(xh1, nodeoff, deg, eidx, mnh, NTOT);
  combine_mfma_kernel<<<CMB_BLOCKS, 256, 0, stream>>>(mnh, xh1, wfrag + 2 * 4096, b2, xf, nullptr);

  // classifier (fp32 input, unquantized)
  classifier_kernel<<<(NTOT + 255) / 256, 256, 0, stream>>>(xf, Wc1, bc1, Wc2, bc2,
                                                            (float*)d_out, NTOT);
}

// Round 2
// 602.004 us; speedup vs baseline: 1.1817x; 1.1044x over previous
//
#include <hip/hip_runtime.h>

#define N_IND 100000
#define N_COM 100000
#define N_TRU 100000
#define NTOT  300000
#define NEDGE 4800000
#define HDIM  64
#define CHUNK 8192
#define NCHUNKS 586   // ceil(NEDGE/CHUNK)
#define NCB 293       // ceil(NTOT/1024) coarse buckets of 1024 nodes
#define PADW 33       // 32 cols + 1 pad (encoder epilogue)
#define NTILES 18750  // NTOT / 16 exactly

typedef float v4f __attribute__((ext_vector_type(4)));
typedef unsigned short v4u __attribute__((ext_vector_type(4)));
typedef _Float16 v8h __attribute__((ext_vector_type(8)));

static __device__ __forceinline__ float elem4(const float4 v, int j) {
  return j == 0 ? v.x : j == 1 ? v.y : j == 2 ? v.z : v.w;
}

// fp32 <-> fp16 (RTN via v_cvt)
static __device__ __forceinline__ unsigned short f2h(float f) {
  _Float16 h = (_Float16)f;
  return __builtin_bit_cast(unsigned short, h);
}
static __device__ __forceinline__ float h2f(unsigned short u) {
  return (float)__builtin_bit_cast(_Float16, u);
}

// Coalesced fp16 epilogue for encoder (256 rows, 2 stages of 32 cols).
static __device__ __forceinline__ void store_rows_f16(
    unsigned short* __restrict__ out, float* __restrict__ st, const float* acc,
    int node0, int rows, int tid, bool active) {
#pragma unroll
  for (int stage = 0; stage < 2; ++stage) {
    __syncthreads();
    if (active) {
#pragma unroll
      for (int j = 0; j < 32; ++j) st[tid * PADW + j] = acc[stage * 32 + j];
    }
    __syncthreads();
#pragma unroll
    for (int it = 0; it < 8; ++it) {
      int e = it * 256 + tid;
      int r = e >> 3;
      int c = (e & 7) * 4;
      if (r < rows) {
        v4u o;
        o.x = f2h(st[r * PADW + c + 0]);
        o.y = f2h(st[r * PADW + c + 1]);
        o.z = f2h(st[r * PADW + c + 2]);
        o.w = f2h(st[r * PADW + c + 3]);
        *(v4u*)(out + (size_t)(node0 + r) * HDIM + stage * 32 + c) = o;
      }
    }
  }
}

// ---------------- encoder: xh[base+n] = fp16(x[n] @ W + b) ----------------
template <int K>
__global__ __launch_bounds__(256, 2) void encode_kernel(
    const float* __restrict__ xin, const float* __restrict__ W,
    const float* __restrict__ b, unsigned short* __restrict__ xhout, int n, int base) {
  __shared__ float st[256 * PADW];
  int tid = threadIdx.x;
  int node0 = blockIdx.x * 256;
  int node = node0 + tid;
  bool active = node < n;
  int rows = min(256, n - node0);
  float acc[HDIM];
  if (active) {
    float4 row[K / 4];
    const float4* xv = (const float4*)(xin + (size_t)node * K);
#pragma unroll
    for (int i = 0; i < K / 4; ++i) row[i] = xv[i];
#pragma unroll
    for (int f = 0; f < HDIM; ++f) acc[f] = b[f];  // uniform -> s_load
#pragma unroll
    for (int k4 = 0; k4 < K / 4; ++k4) {
#pragma unroll
      for (int j = 0; j < 4; ++j) {
        float xs = elem4(row[k4], j);
        int k = k4 * 4 + j;
#pragma unroll
        for (int f = 0; f < HDIM; ++f) acc[f] += xs * W[k * HDIM + f];
      }
    }
  }
  store_rows_f16(xhout + (size_t)base * HDIM, st, acc, node0, rows, tid, active);
}

// ---------------- weight prep: fp32 -> fp16, swizzled to B-fragment order ----------------
// frag layout per 64x64 matrix: out[ts*512 + l*8 + j] = W[s*32 + (l>>4)*8 + j][t*16 + (l&15)]
// where ts = t*2+s. A v8h load at index (ts*64 + lane) yields lane's B fragment.
__global__ __launch_bounds__(256) void prep_weights_kernel(
    const float* __restrict__ W1l, const float* __restrict__ W1r,
    const float* __restrict__ W2l, const float* __restrict__ W2r,
    unsigned short* __restrict__ out) {
  const float* Ws[4] = {W1l, W1r, W2l, W2r};
  int tid = threadIdx.x;
  for (int m = 0; m < 4; ++m) {
    const float* W = Ws[m];
    unsigned short* o = out + m * 4096;
    for (int idx = tid; idx < 4096; idx += 256) {
      int j = idx & 7;
      int l = (idx >> 3) & 63;
      int ts = idx >> 9;
      int t = ts >> 1, s = ts & 1;
      int k = s * 32 + (l >> 4) * 8 + j;
      int n = t * 16 + (l & 15);
      o[idx] = f2h(W[k * HDIM + n]);
    }
  }
}

// ---------------- coarse histogram: LDS-aggregated, 293 bins ----------------
__global__ __launch_bounds__(256) void coarse_hist_kernel(const int* __restrict__ dst,
                                                          int* __restrict__ chist, int e) {
  __shared__ int h[NCB];
  int tid = threadIdx.x;
  int start = blockIdx.x * CHUNK;
  int len = min(CHUNK, e - start);
  for (int i = tid; i < NCB; i += 256) h[i] = 0;
  __syncthreads();
  for (int i = tid; i < len; i += 256) atomicAdd(&h[dst[start + i] >> 10], 1);
  __syncthreads();
  for (int b = tid; b < NCB; b += 256) {
    int c = h[b];
    if (c > 0) atomicAdd(&chist[b], c);
  }
}

// ---------------- exclusive scan of 293 coarse counts ----------------
__global__ __launch_bounds__(512) void coarse_scan_kernel(const int* __restrict__ chist,
                                                          int* __restrict__ cbase,
                                                          int* __restrict__ ccur) {
  __shared__ int sv[512];
  int t = threadIdx.x;
  sv[t] = (t < NCB) ? chist[t] : 0;
  __syncthreads();
  for (int o = 1; o < 512; o <<= 1) {
    int y = (t >= o) ? sv[t - o] : 0;
    __syncthreads();
    sv[t] += y;
    __syncthreads();
  }
  if (t < NCB) {
    int ex = (t == 0) ? 0 : sv[t - 1];
    cbase[t] = ex;
    ccur[t] = ex;
  }
}

// ---------------- coarse scatter: LDS-staged local sort, coalesced run writes ----------
__global__ __launch_bounds__(256) void coarse_scatter_kernel(
    const int* __restrict__ src, const int* __restrict__ dst,
    int* __restrict__ ccur, unsigned* __restrict__ packed, int e) {
  __shared__ int h[NCB];        // per-bucket counts, then rank counters
  __shared__ int gofs[NCB];     // lbase[b] - lofs[b]  (global offset per slot)
  __shared__ int sv[512];       // Hillis-Steele scan buffer
  __shared__ unsigned vals[CHUNK];        // locally sorted packed values
  __shared__ unsigned short bid[CHUNK];   // bucket id per slot
  int tid = threadIdx.x;
  int start = blockIdx.x * CHUNK;
  int len = min(CHUNK, e - start);

  for (int i = tid; i < NCB; i += 256) h[i] = 0;
  __syncthreads();

  // Phase A: histogram; keep dst values in registers for phase C.
  int dreg[CHUNK / 256];
#pragma unroll
  for (int k = 0; k < CHUNK / 256; ++k) {
    int i = k * 256 + tid;
    dreg[k] = (i < len) ? dst[start + i] : -1;
    if (i < len) atomicAdd(&h[dreg[k] >> 10], 1);
  }
  __syncthreads();

  // Phase B: block-local inclusive scan of 293 counts (512-wide Hillis-Steele,
  // 256 threads x 2 slots). Then exclusive base lofs, reserve global run, set ranks.
  sv[tid] = (tid < NCB) ? h[tid] : 0;
  sv[tid + 256] = (tid + 256 < NCB) ? h[tid + 256] : 0;
  __syncthreads();
  for (int o = 1; o < 512; o <<= 1) {
    int y0 = (tid >= o) ? sv[tid - o] : 0;
    int y1 = sv[tid + 256 - o];  // tid+256 >= o always (o <= 256)
    __syncthreads();
    sv[tid] += y0;
    sv[tid + 256] += y1;
    __syncthreads();
  }
  for (int b = tid; b < NCB; b += 256) {
    int c = h[b];
    int lo = (b == 0) ? 0 : sv[b - 1];
    int gb = (c > 0) ? atomicAdd(&ccur[b], c) : 0;  // reserve contiguous run
    gofs[b] = gb - lo;
    h[b] = lo;  // reuse as rank counter
  }
  __syncthreads();

  // Phase C: scatter into LDS in locally-sorted order.
#pragma unroll
  for (int k = 0; k < CHUNK / 256; ++k) {
    int i = k * 256 + tid;
    if (i < len) {
      int d = dreg[k];
      int s = src[start + i];
      int b = d >> 10;
      int slot = atomicAdd(&h[b], 1);
      vals[slot] = ((unsigned)s << 10) | (unsigned)(d & 1023);
      bid[slot] = (unsigned short)b;
    }
  }
  __syncthreads();

  // Phase D: coalesced sweep; within each bucket run, consecutive slots map to
  // consecutive global addresses.
  for (int i = tid; i < len; i += 256) {
    int b = bid[i];
    packed[gofs[b] + i] = vals[i];
  }
}

// ---------------- per-coarse-bucket counting sort -> node-grouped CSR ----------------
__global__ __launch_bounds__(256) void sort_coarse_kernel(
    const unsigned* __restrict__ packed, const int* __restrict__ cbase,
    const int* __restrict__ chist, int* __restrict__ eidx,
    int* __restrict__ nodeoff, int* __restrict__ deg) {
  __shared__ int cnts[1024];
  __shared__ int cur[1024];
  __shared__ int part[256];
  int cb = blockIdx.x;
  int tid = threadIdx.x;
  for (int i = tid; i < 1024; i += 256) cnts[i] = 0;
  __syncthreads();
  int base = cbase[cb];
  int cnt = chist[cb];
  for (int i = tid; i < cnt; i += 256)
    atomicAdd(&cnts[packed[base + i] & 1023u], 1);
  __syncthreads();
  int c0 = cnts[4 * tid + 0], c1 = cnts[4 * tid + 1];
  int c2 = cnts[4 * tid + 2], c3 = cnts[4 * tid + 3];
  part[tid] = c0 + c1 + c2 + c3;
  __syncthreads();
  for (int o = 1; o < 256; o <<= 1) {
    int y = (tid >= o) ? part[tid - o] : 0;
    __syncthreads();
    part[tid] += y;
    __syncthreads();
  }
  int pre = (tid == 0) ? 0 : part[tid - 1];
  int e0 = pre, e1 = e0 + c0, e2 = e1 + c1, e3 = e2 + c2;
  cur[4 * tid + 0] = e0; cur[4 * tid + 1] = e1;
  cur[4 * tid + 2] = e2; cur[4 * tid + 3] = e3;
  int nodebase = (cb << 10) + 4 * tid;
  if (nodebase + 0 < NTOT) { deg[nodebase + 0] = c0; nodeoff[nodebase + 0] = base + e0; }
  if (nodebase + 1 < NTOT) { deg[nodebase + 1] = c1; nodeoff[nodebase + 1] = base + e1; }
  if (nodebase + 2 < NTOT) { deg[nodebase + 2] = c2; nodeoff[nodebase + 2] = base + e2; }
  if (nodebase + 3 < NTOT) { deg[nodebase + 3] = c3; nodeoff[nodebase + 3] = base + e3; }
  __syncthreads();
  for (int i = tid; i < cnt; i += 256) {
    unsigned pr = packed[base + i];
    int dl = (int)(pr & 1023u);
    int r = atomicAdd(&cur[dl], 1);
    eidx[base + r] = (int)(pr >> 10);  // 64 KB region exclusive to this block
  }
}

// ---------------- fused: aggregate -> LDS mean -> MFMA combine -> output ----------------
// Block = 256 threads = one 16-node tile. Phase 1: gather-mean (16 lanes/node, identical
// to the proven aggregate loop) into LDS [16][72] fp16 (pad 16 B/row -> bank-spread,
// v8h-aligned MFMA A-fragments). Phase 2: 4 waves, wave wid computes output cols
// [wid*16, wid*16+16) via 4 MFMAs, relu -> fp32 LDS stage [16][68].
// Phase 3: LAYER2=false: coalesced fp16 store of the 16x64 tile.
//          LAYER2=true : classifier fused — h=relu(x@Wc1+bc1), out=h@Wc2+bc2, fp32,
//                        numerically identical order to the old classifier_kernel.
#define SMPAD 72
template <bool LAYER2>
__global__ __launch_bounds__(256, 4) void agg_combine_kernel(
    const unsigned short* __restrict__ xh, const int* __restrict__ off,
    const int* __restrict__ deg, const int* __restrict__ eidx,
    const unsigned short* __restrict__ wfrag,  // this layer's 2 matrices
    const float* __restrict__ bb,
    unsigned short* __restrict__ outh,         // layer1 output (fp16)
    const float* __restrict__ Wc1, const float* __restrict__ bc1,
    const float* __restrict__ Wc2, const float* __restrict__ bc2,
    float* __restrict__ dout) {                // layer2 classifier output
  __shared__ unsigned short smean[16 * SMPAD];
  __shared__ float st[16 * 68 + 8];
  __shared__ float sW1[LAYER2 ? 2048 : 8];
  int tid = threadIdx.x;
  int node0 = blockIdx.x * 16;

  // ---- phase 1: aggregate (gather loop identical to previous aggregate_kernel) ----
  {
    int nit = tid >> 4;       // node in tile
    int lane16 = tid & 15;
    int node = node0 + nit;
    int start = off[node];
    int d = deg[node];
    const v4u* xv = (const v4u*)xh;   // row = 16 x v4u (128 B)
    float4 a0 = make_float4(0.f, 0.f, 0.f, 0.f);
    float4 a1 = make_float4(0.f, 0.f, 0.f, 0.f);
    float4 a2 = make_float4(0.f, 0.f, 0.f, 0.f);
    float4 a3 = make_float4(0.f, 0.f, 0.f, 0.f);
    int i = 0;
    for (; i + 4 <= d; i += 4) {
      int s0 = eidx[start + i + 0];
      int s1 = eidx[start + i + 1];
      int s2 = eidx[start + i + 2];
      int s3 = eidx[start + i + 3];
      v4u v0 = xv[(size_t)s0 * 16 + lane16];
      v4u v1 = xv[(size_t)s1 * 16 + lane16];
      v4u v2 = xv[(size_t)s2 * 16 + lane16];
      v4u v3 = xv[(size_t)s3 * 16 + lane16];
      a0.x += h2f(v0.x); a0.y += h2f(v0.y); a0.z += h2f(v0.z); a0.w += h2f(v0.w);
      a1.x += h2f(v1.x); a1.y += h2f(v1.y); a1.z += h2f(v1.z); a1.w += h2f(v1.w);
      a2.x += h2f(v2.x); a2.y += h2f(v2.y); a2.z += h2f(v2.z); a2.w += h2f(v2.w);
      a3.x += h2f(v3.x); a3.y += h2f(v3.y); a3.z += h2f(v3.z); a3.w += h2f(v3.w);
    }
    for (; i < d; ++i) {
      int s = eidx[start + i];
      v4u v = xv[(size_t)s * 16 + lane16];
      a0.x += h2f(v.x); a0.y += h2f(v.y); a0.z += h2f(v.z); a0.w += h2f(v.w);
    }
    float inv = 1.0f / (float)(d > 0 ? d : 1);
    v4u o;
    o.x = f2h((a0.x + a1.x + a2.x + a3.x) * inv);
    o.y = f2h((a0.y + a1.y + a2.y + a3.y) * inv);
    o.z = f2h((a0.z + a1.z + a2.z + a3.z) * inv);
    o.w = f2h((a0.w + a1.w + a2.w + a3.w) * inv);
    *(v4u*)&smean[nit * SMPAD + lane16 * 4] = o;
  }
  if (LAYER2) {
    for (int i = tid; i < 2048; i += 256) sW1[i] = Wc1[i];
  }
  __syncthreads();

  // ---- phase 2: combine; wave wid owns output col block t = wid ----
  int wid = tid >> 6;
  int lane = tid & 63;
  int mlo = lane & 15;
  int quad = lane >> 4;
  {
    const v8h* wf = (const v8h*)wfrag;
    v8h BL0 = wf[(wid * 2 + 0) * 64 + lane];
    v8h BL1 = wf[(wid * 2 + 1) * 64 + lane];
    v8h BR0 = wf[512 + (wid * 2 + 0) * 64 + lane];
    v8h BR1 = wf[512 + (wid * 2 + 1) * 64 + lane];
    float bias = bb[wid * 16 + mlo];
    v8h Am0 = *(const v8h*)&smean[mlo * SMPAD + quad * 8];
    v8h Am1 = *(const v8h*)&smean[mlo * SMPAD + quad * 8 + 32];
    const _Float16* xrow = (const _Float16*)xh + (size_t)(node0 + mlo) * HDIM + quad * 8;
    v8h Ax0 = *(const v8h*)(xrow);
    v8h Ax1 = *(const v8h*)(xrow + 32);
    v4f acc = {bias, bias, bias, bias};
    acc = __builtin_amdgcn_mfma_f32_16x16x32_f16(Am0, BL0, acc, 0, 0, 0);
    acc = __builtin_amdgcn_mfma_f32_16x16x32_f16(Am1, BL1, acc, 0, 0, 0);
    acc = __builtin_amdgcn_mfma_f32_16x16x32_f16(Ax0, BR0, acc, 0, 0, 0);
    acc = __builtin_amdgcn_mfma_f32_16x16x32_f16(Ax1, BR1, acc, 0, 0, 0);
#pragma unroll
    for (int r = 0; r < 4; ++r)
      st[(quad * 4 + r) * 68 + wid * 16 + mlo] = fmaxf(acc[r], 0.f);
  }
  __syncthreads();

  // ---- phase 3: output ----
  if (!LAYER2) {
    // coalesced fp16 store of the 16x64 tile: row = tid>>4, 4 cols per thread
    int r = tid >> 4;
    int c = (tid & 15) * 4;
    const float* ap = &st[r * 68 + c];
    v4u o;
    o.x = f2h(ap[0]); o.y = f2h(ap[1]); o.z = f2h(ap[2]); o.w = f2h(ap[3]);
    *(v4u*)(outh + (size_t)(node0 + r) * HDIM + c) = o;
  } else {
    // classifier: 16 threads/node, 2 hidden units each, shfl-tree reduce
    int nd = tid >> 4;
    int f = (tid & 15) * 2;
    float h0 = bc1[f], h1 = bc1[f + 1];
    const float* xr = &st[nd * 68];
#pragma unroll
    for (int k = 0; k < 64; ++k) {
      float xv = xr[k];
      h0 += xv * sW1[k * 32 + f];
      h1 += xv * sW1[k * 32 + f + 1];
    }
    h0 = fmaxf(h0, 0.f);
    h1 = fmaxf(h1, 0.f);
    float o0 = h0 * Wc2[f * 2 + 0] + h1 * Wc2[(f + 1) * 2 + 0];
    float o1 = h0 * Wc2[f * 2 + 1] + h1 * Wc2[(f + 1) * 2 + 1];
#pragma unroll
    for (int m = 8; m >= 1; m >>= 1) {
      o0 += __shfl_xor(o0, m);
      o1 += __shfl_xor(o1, m);
    }
    if ((tid & 15) == 0) {
      float2 ov;
      ov.x = o0 + bc2[0];
      ov.y = o1 + bc2[1];
      *(float2*)(dout + (size_t)(node0 + nd) * 2) = ov;
    }
  }
}

extern "C" void kernel_launch(void* const* d_in, const int* in_sizes, int n_in,
                              void* d_out, int out_size, void* d_ws, size_t ws_size,
                              hipStream_t stream) {
  const float* x_ind = (const float*)d_in[0];
  const float* x_com = (const float*)d_in[1];
  const float* x_tru = (const float*)d_in[2];
  const int*   ei    = (const int*)d_in[3];
  const float* W_ind = (const float*)d_in[4];
  const float* b_ind = (const float*)d_in[5];
  const float* W_com = (const float*)d_in[6];
  const float* b_com = (const float*)d_in[7];
  const float* W_tru = (const float*)d_in[8];
  const float* b_tru = (const float*)d_in[9];
  const float* W1l = (const float*)d_in[10];
  const float* W1r = (const float*)d_in[11];
  const float* b1  = (const float*)d_in[12];
  const float* W2l = (const float*)d_in[13];
  const float* W2r = (const float*)d_in[14];
  const float* b2  = (const float*)d_in[15];
  const float* Wc1 = (const float*)d_in[16];
  const float* bc1 = (const float*)d_in[17];
  const float* Wc2 = (const float*)d_in[18];
  const float* bc2 = (const float*)d_in[19];

  const int* srcp = ei;           // edge_index[0]
  const int* dstp = ei + NEDGE;   // edge_index[1]

  // workspace layout (~118 MB; previous rounds proved >=252 MB available)
  size_t fcount = (size_t)NTOT * HDIM;
  unsigned* packed = (unsigned*)d_ws;                     // edge staging (19.2 MB)
  unsigned short* xh0 = (unsigned short*)(packed + NEDGE);  // fp16 layer-0 features
  unsigned short* xh1 = xh0 + fcount;                       // fp16 layer-1 features
  int* eidx    = (int*)(xh1 + fcount);
  int* nodeoff = eidx + NEDGE;
  int* deg     = nodeoff + NTOT;
  int* chist   = deg + NTOT;
  int* cbase   = chist + NCB;
  int* ccur    = cbase + NCB;
  // 16B-aligned weight-fragment area (4 matrices x 4096 halfs = 32 KB)
  unsigned short* wfrag = (unsigned short*)((((size_t)(ccur + NCB)) + 15) & ~(size_t)15);
  size_t needed = (size_t)((char*)(wfrag + 4 * 4096) - (char*)d_ws) + 64;
  if (ws_size < needed) return;  // would corrupt; fail visibly instead

  (void)hipMemsetAsync(chist, 0, (size_t)NCB * sizeof(int), stream);

  // weight prep (fp16 + fragment swizzle), independent of everything else
  prep_weights_kernel<<<1, 256, 0, stream>>>(W1l, W1r, W2l, W2r, wfrag);

  // encoders (write fp16 xh0; independent of edge pipeline)
  encode_kernel<32><<<(N_IND + 255) / 256, 256, 0, stream>>>(x_ind, W_ind, b_ind, xh0, N_IND, 0);
  encode_kernel<48><<<(N_COM + 255) / 256, 256, 0, stream>>>(x_com, W_com, b_com, xh0, N_COM, N_IND);
  encode_kernel<24><<<(N_TRU + 255) / 256, 256, 0, stream>>>(x_tru, W_tru, b_tru, xh0, N_TRU, N_IND + N_COM);

  // coarse partition -> per-coarse-bucket counting sort -> node-grouped CSR
  coarse_hist_kernel<<<NCHUNKS, 256, 0, stream>>>(dstp, chist, NEDGE);
  coarse_scan_kernel<<<1, 512, 0, stream>>>(chist, cbase, ccur);
  coarse_scatter_kernel<<<NCHUNKS, 256, 0, stream>>>(srcp, dstp, ccur, packed, NEDGE);
  sort_coarse_kernel<<<NCB, 256, 0, stream>>>(packed, cbase, chist, eidx, nodeoff, deg);

  // SAGE layer 1 fused: aggregate -> LDS -> MFMA combine -> fp16 xh1
  agg_combine_kernel<false><<<NTILES, 256, 0, stream>>>(
      xh0, nodeoff, deg, eidx, wfrag, b1, xh1, nullptr, nullptr, nullptr, nullptr, nullptr);

  // SAGE layer 2 fused: aggregate -> LDS -> MFMA combine -> classifier -> d_out
  agg_combine_kernel<true><<<NTILES, 256, 0, stream>>>(
      xh1, nodeoff, deg, eidx, wfrag + 2 * 4096, b2, nullptr, Wc1, bc1, Wc2, bc2,
      (float*)d_out);
}

// Round 3
// 597.640 us; speedup vs baseline: 1.1903x; 1.0073x over previous
//
#include <hip/hip_runtime.h>

#define N_IND 100000
#define N_COM 100000
#define N_TRU 100000
#define NTOT  300000
#define NEDGE 4800000
#define HDIM  64
#define CHUNK 8192
#define NCHUNKS 586   // ceil(NEDGE/CHUNK)
#define NCB 293       // ceil(NTOT/1024) coarse buckets of 1024 nodes
#define PADW 33       // 32 cols + 1 pad (encoder epilogue)
#define NTILES 18750  // NTOT / 16 exactly

typedef float v4f __attribute__((ext_vector_type(4)));
typedef unsigned short v4u __attribute__((ext_vector_type(4)));
typedef _Float16 v8h __attribute__((ext_vector_type(8)));

static __device__ __forceinline__ float elem4(const float4 v, int j) {
  return j == 0 ? v.x : j == 1 ? v.y : j == 2 ? v.z : v.w;
}

// fp32 <-> fp16 (RTN via v_cvt)
static __device__ __forceinline__ unsigned short f2h(float f) {
  _Float16 h = (_Float16)f;
  return __builtin_bit_cast(unsigned short, h);
}
static __device__ __forceinline__ float h2f(unsigned short u) {
  return (float)__builtin_bit_cast(_Float16, u);
}

// acc += (float)lo_half(pk); acc2 += (float)hi_half(pk) — one v_fma_mix_f32 each.
// Bitwise identical to v_cvt_f32_f16 + v_add_f32 (exact convert, x1.0 exact, one round).
static __device__ __forceinline__ void fmix2(float& alo, float& ahi, unsigned pk) {
  asm("v_fma_mix_f32 %0, %1, 1.0, %0 op_sel:[0,0,0] op_sel_hi:[1,0,0]"
      : "+v"(alo) : "v"(pk));
  asm("v_fma_mix_f32 %0, %1, 1.0, %0 op_sel:[1,0,0] op_sel_hi:[1,0,0]"
      : "+v"(ahi) : "v"(pk));
}

// Coalesced fp16 epilogue for encoder (256 rows, 2 stages of 32 cols).
static __device__ __forceinline__ void store_rows_f16(
    unsigned short* __restrict__ out, float* __restrict__ st, const float* acc,
    int node0, int rows, int tid, bool active) {
#pragma unroll
  for (int stage = 0; stage < 2; ++stage) {
    __syncthreads();
    if (active) {
#pragma unroll
      for (int j = 0; j < 32; ++j) st[tid * PADW + j] = acc[stage * 32 + j];
    }
    __syncthreads();
#pragma unroll
    for (int it = 0; it < 8; ++it) {
      int e = it * 256 + tid;
      int r = e >> 3;
      int c = (e & 7) * 4;
      if (r < rows) {
        v4u o;
        o.x = f2h(st[r * PADW + c + 0]);
        o.y = f2h(st[r * PADW + c + 1]);
        o.z = f2h(st[r * PADW + c + 2]);
        o.w = f2h(st[r * PADW + c + 3]);
        *(v4u*)(out + (size_t)(node0 + r) * HDIM + stage * 32 + c) = o;
      }
    }
  }
}

// ---------------- encoder: xh[base+n] = fp16(x[n] @ W + b) ----------------
template <int K>
__global__ __launch_bounds__(256, 2) void encode_kernel(
    const float* __restrict__ xin, const float* __restrict__ W,
    const float* __restrict__ b, unsigned short* __restrict__ xhout, int n, int base) {
  __shared__ float st[256 * PADW];
  int tid = threadIdx.x;
  int node0 = blockIdx.x * 256;
  int node = node0 + tid;
  bool active = node < n;
  int rows = min(256, n - node0);
  float acc[HDIM];
  if (active) {
    float4 row[K / 4];
    const float4* xv = (const float4*)(xin + (size_t)node * K);
#pragma unroll
    for (int i = 0; i < K / 4; ++i) row[i] = xv[i];
#pragma unroll
    for (int f = 0; f < HDIM; ++f) acc[f] = b[f];  // uniform -> s_load
#pragma unroll
    for (int k4 = 0; k4 < K / 4; ++k4) {
#pragma unroll
      for (int j = 0; j < 4; ++j) {
        float xs = elem4(row[k4], j);
        int k = k4 * 4 + j;
#pragma unroll
        for (int f = 0; f < HDIM; ++f) acc[f] += xs * W[k * HDIM + f];
      }
    }
  }
  store_rows_f16(xhout + (size_t)base * HDIM, st, acc, node0, rows, tid, active);
}

// ---------------- weight prep: fp32 -> fp16, swizzled to B-fragment order ----------------
// frag layout per 64x64 matrix: out[ts*512 + l*8 + j] = W[s*32 + (l>>4)*8 + j][t*16 + (l&15)]
// where ts = t*2+s. A v8h load at index (ts*64 + lane) yields lane's B fragment.
__global__ __launch_bounds__(256) void prep_weights_kernel(
    const float* __restrict__ W1l, const float* __restrict__ W1r,
    const float* __restrict__ W2l, const float* __restrict__ W2r,
    unsigned short* __restrict__ out) {
  const float* Ws[4] = {W1l, W1r, W2l, W2r};
  int tid = threadIdx.x;
  for (int m = 0; m < 4; ++m) {
    const float* W = Ws[m];
    unsigned short* o = out + m * 4096;
    for (int idx = tid; idx < 4096; idx += 256) {
      int j = idx & 7;
      int l = (idx >> 3) & 63;
      int ts = idx >> 9;
      int t = ts >> 1, s = ts & 1;
      int k = s * 32 + (l >> 4) * 8 + j;
      int n = t * 16 + (l & 15);
      o[idx] = f2h(W[k * HDIM + n]);
    }
  }
}

// ---------------- coarse histogram: LDS-aggregated, 293 bins ----------------
__global__ __launch_bounds__(256) void coarse_hist_kernel(const int* __restrict__ dst,
                                                          int* __restrict__ chist, int e) {
  __shared__ int h[NCB];
  int tid = threadIdx.x;
  int start = blockIdx.x * CHUNK;
  int len = min(CHUNK, e - start);
  for (int i = tid; i < NCB; i += 256) h[i] = 0;
  __syncthreads();
  for (int i = tid; i < len; i += 256) atomicAdd(&h[dst[start + i] >> 10], 1);
  __syncthreads();
  for (int b = tid; b < NCB; b += 256) {
    int c = h[b];
    if (c > 0) atomicAdd(&chist[b], c);
  }
}

// ---------------- exclusive scan of 293 coarse counts ----------------
__global__ __launch_bounds__(512) void coarse_scan_kernel(const int* __restrict__ chist,
                                                          int* __restrict__ cbase,
                                                          int* __restrict__ ccur) {
  __shared__ int sv[512];
  int t = threadIdx.x;
  sv[t] = (t < NCB) ? chist[t] : 0;
  __syncthreads();
  for (int o = 1; o < 512; o <<= 1) {
    int y = (t >= o) ? sv[t - o] : 0;
    __syncthreads();
    sv[t] += y;
    __syncthreads();
  }
  if (t < NCB) {
    int ex = (t == 0) ? 0 : sv[t - 1];
    cbase[t] = ex;
    ccur[t] = ex;
  }
}

// ---------------- coarse scatter: LDS-staged local sort, coalesced run writes ----------
__global__ __launch_bounds__(256) void coarse_scatter_kernel(
    const int* __restrict__ src, const int* __restrict__ dst,
    int* __restrict__ ccur, unsigned* __restrict__ packed, int e) {
  __shared__ int h[NCB];        // per-bucket counts, then rank counters
  __shared__ int gofs[NCB];     // lbase[b] - lofs[b]  (global offset per slot)
  __shared__ int sv[512];       // Hillis-Steele scan buffer
  __shared__ unsigned vals[CHUNK];        // locally sorted packed values
  __shared__ unsigned short bid[CHUNK];   // bucket id per slot
  int tid = threadIdx.x;
  int start = blockIdx.x * CHUNK;
  int len = min(CHUNK, e - start);

  for (int i = tid; i < NCB; i += 256) h[i] = 0;
  __syncthreads();

  // Phase A: histogram; keep dst values in registers for phase C.
  int dreg[CHUNK / 256];
#pragma unroll
  for (int k = 0; k < CHUNK / 256; ++k) {
    int i = k * 256 + tid;
    dreg[k] = (i < len) ? dst[start + i] : -1;
    if (i < len) atomicAdd(&h[dreg[k] >> 10], 1);
  }
  __syncthreads();

  // Phase B: block-local inclusive scan of 293 counts (512-wide Hillis-Steele,
  // 256 threads x 2 slots). Then exclusive base lofs, reserve global run, set ranks.
  sv[tid] = (tid < NCB) ? h[tid] : 0;
  sv[tid + 256] = (tid + 256 < NCB) ? h[tid + 256] : 0;
  __syncthreads();
  for (int o = 1; o < 512; o <<= 1) {
    int y0 = (tid >= o) ? sv[tid - o] : 0;
    int y1 = sv[tid + 256 - o];  // tid+256 >= o always (o <= 256)
    __syncthreads();
    sv[tid] += y0;
    sv[tid + 256] += y1;
    __syncthreads();
  }
  for (int b = tid; b < NCB; b += 256) {
    int c = h[b];
    int lo = (b == 0) ? 0 : sv[b - 1];
    int gb = (c > 0) ? atomicAdd(&ccur[b], c) : 0;  // reserve contiguous run
    gofs[b] = gb - lo;
    h[b] = lo;  // reuse as rank counter
  }
  __syncthreads();

  // Phase C: scatter into LDS in locally-sorted order.
#pragma unroll
  for (int k = 0; k < CHUNK / 256; ++k) {
    int i = k * 256 + tid;
    if (i < len) {
      int d = dreg[k];
      int s = src[start + i];
      int b = d >> 10;
      int slot = atomicAdd(&h[b], 1);
      vals[slot] = ((unsigned)s << 10) | (unsigned)(d & 1023);
      bid[slot] = (unsigned short)b;
    }
  }
  __syncthreads();

  // Phase D: coalesced sweep; within each bucket run, consecutive slots map to
  // consecutive global addresses.
  for (int i = tid; i < len; i += 256) {
    int b = bid[i];
    packed[gofs[b] + i] = vals[i];
  }
}

// ---------------- per-coarse-bucket counting sort -> node-grouped CSR ----------------
__global__ __launch_bounds__(256) void sort_coarse_kernel(
    const unsigned* __restrict__ packed, const int* __restrict__ cbase,
    const int* __restrict__ chist, int* __restrict__ eidx,
    int* __restrict__ nodeoff, int* __restrict__ deg) {
  __shared__ int cnts[1024];
  __shared__ int cur[1024];
  __shared__ int part[256];
  int cb = blockIdx.x;
  int tid = threadIdx.x;
  for (int i = tid; i < 1024; i += 256) cnts[i] = 0;
  __syncthreads();
  int base = cbase[cb];
  int cnt = chist[cb];
  for (int i = tid; i < cnt; i += 256)
    atomicAdd(&cnts[packed[base + i] & 1023u], 1);
  __syncthreads();
  int c0 = cnts[4 * tid + 0], c1 = cnts[4 * tid + 1];
  int c2 = cnts[4 * tid + 2], c3 = cnts[4 * tid + 3];
  part[tid] = c0 + c1 + c2 + c3;
  __syncthreads();
  for (int o = 1; o < 256; o <<= 1) {
    int y = (tid >= o) ? part[tid - o] : 0;
    __syncthreads();
    part[tid] += y;
    __syncthreads();
  }
  int pre = (tid == 0) ? 0 : part[tid - 1];
  int e0 = pre, e1 = e0 + c0, e2 = e1 + c1, e3 = e2 + c2;
  cur[4 * tid + 0] = e0; cur[4 * tid + 1] = e1;
  cur[4 * tid + 2] = e2; cur[4 * tid + 3] = e3;
  int nodebase = (cb << 10) + 4 * tid;
  if (nodebase + 0 < NTOT) { deg[nodebase + 0] = c0; nodeoff[nodebase + 0] = base + e0; }
  if (nodebase + 1 < NTOT) { deg[nodebase + 1] = c1; nodeoff[nodebase + 1] = base + e1; }
  if (nodebase + 2 < NTOT) { deg[nodebase + 2] = c2; nodeoff[nodebase + 2] = base + e2; }
  if (nodebase + 3 < NTOT) { deg[nodebase + 3] = c3; nodeoff[nodebase + 3] = base + e3; }
  __syncthreads();
  for (int i = tid; i < cnt; i += 256) {
    unsigned pr = packed[base + i];
    int dl = (int)(pr & 1023u);
    int r = atomicAdd(&cur[dl], 1);
    eidx[base + r] = (int)(pr >> 10);  // 64 KB region exclusive to this block
  }
}

// ---------------- fused: aggregate -> LDS mean -> MFMA combine -> output ----------------
// Block = 256 threads = one 16-node tile. Phase 1: gather-mean (16 lanes/node) with
// v_fma_mix_f32 accumulation (1 VALU/element, bitwise == cvt+add) and 32-bit row
// offsets (saddr+voffset addressing), 8 rows in flight/lane. Edge e -> acc bank e&3,
// ascending order within bank -> reduction order identical to previous version.
// Phase 2: 4 waves, wave wid computes output cols [wid*16, wid*16+16) via 4 MFMAs,
// relu -> fp32 LDS stage [16][68].
// Phase 3: LAYER2=false: coalesced fp16 store. LAYER2=true: fused classifier.
#define SMPAD 72
template <bool LAYER2>
__global__ __launch_bounds__(256, 4) void agg_combine_kernel(
    const unsigned short* __restrict__ xh, const int* __restrict__ off,
    const int* __restrict__ deg, const int* __restrict__ eidx,
    const unsigned short* __restrict__ wfrag,  // this layer's 2 matrices
    const float* __restrict__ bb,
    unsigned short* __restrict__ outh,         // layer1 output (fp16)
    const float* __restrict__ Wc1, const float* __restrict__ bc1,
    const float* __restrict__ Wc2, const float* __restrict__ bc2,
    float* __restrict__ dout) {                // layer2 classifier output
  __shared__ unsigned short smean[16 * SMPAD];
  __shared__ float st[16 * 68 + 8];
  __shared__ float sW1[LAYER2 ? 2048 : 8];
  int tid = threadIdx.x;
  int node0 = blockIdx.x * 16;

  // ---- phase 1: aggregate ----
  {
    int nit = tid >> 4;       // node in tile
    int lane16 = tid & 15;
    int node = node0 + nit;
    int start = off[node];
    int d = deg[node];
    const char* xb = (const char*)xh;
    unsigned rofs = (unsigned)(lane16 << 3);  // byte offset of this lane in a 128 B row
    float acc[16];
#pragma unroll
    for (int j = 0; j < 16; ++j) acc[j] = 0.f;
    int i = 0;
    for (; i + 8 <= d; i += 8) {
      const int* ep = eidx + start + i;
      int s[8];
#pragma unroll
      for (int k = 0; k < 8; ++k) s[k] = ep[k];
      uint2 v[8];
#pragma unroll
      for (int k = 0; k < 8; ++k)
        v[k] = *(const uint2*)(xb + ((((unsigned)s[k]) << 7) + rofs));
#pragma unroll
      for (int k = 0; k < 8; ++k) {
        fmix2(acc[(k & 3) * 4 + 0], acc[(k & 3) * 4 + 1], v[k].x);
        fmix2(acc[(k & 3) * 4 + 2], acc[(k & 3) * 4 + 3], v[k].y);
      }
    }
    if (i + 4 <= d) {
      const int* ep = eidx + start + i;
      int s[4];
#pragma unroll
      for (int k = 0; k < 4; ++k) s[k] = ep[k];
      uint2 v[4];
#pragma unroll
      for (int k = 0; k < 4; ++k)
        v[k] = *(const uint2*)(xb + ((((unsigned)s[k]) << 7) + rofs));
#pragma unroll
      for (int k = 0; k < 4; ++k) {
        fmix2(acc[k * 4 + 0], acc[k * 4 + 1], v[k].x);
        fmix2(acc[k * 4 + 2], acc[k * 4 + 3], v[k].y);
      }
      i += 4;
    }
    for (; i < d; ++i) {
      int s = eidx[start + i];
      uint2 v = *(const uint2*)(xb + ((((unsigned)s) << 7) + rofs));
      fmix2(acc[0], acc[1], v.x);
      fmix2(acc[2], acc[3], v.y);
    }
    float inv = 1.0f / (float)(d > 0 ? d : 1);
    v4u o;
    o.x = f2h((acc[0] + acc[4] + acc[8] + acc[12]) * inv);
    o.y = f2h((acc[1] + acc[5] + acc[9] + acc[13]) * inv);
    o.z = f2h((acc[2] + acc[6] + acc[10] + acc[14]) * inv);
    o.w = f2h((acc[3] + acc[7] + acc[11] + acc[15]) * inv);
    *(v4u*)&smean[nit * SMPAD + lane16 * 4] = o;
  }
  if (LAYER2) {
    for (int i = tid; i < 2048; i += 256) sW1[i] = Wc1[i];
  }
  __syncthreads();

  // ---- phase 2: combine; wave wid owns output col block t = wid ----
  int wid = tid >> 6;
  int lane = tid & 63;
  int mlo = lane & 15;
  int quad = lane >> 4;
  {
    const v8h* wf = (const v8h*)wfrag;
    v8h BL0 = wf[(wid * 2 + 0) * 64 + lane];
    v8h BL1 = wf[(wid * 2 + 1) * 64 + lane];
    v8h BR0 = wf[512 + (wid * 2 + 0) * 64 + lane];
    v8h BR1 = wf[512 + (wid * 2 + 1) * 64 + lane];
    float bias = bb[wid * 16 + mlo];
    v8h Am0 = *(const v8h*)&smean[mlo * SMPAD + quad * 8];
    v8h Am1 = *(const v8h*)&smean[mlo * SMPAD + quad * 8 + 32];
    const _Float16* xrow = (const _Float16*)xh + (size_t)(node0 + mlo) * HDIM + quad * 8;
    v8h Ax0 = *(const v8h*)(xrow);
    v8h Ax1 = *(const v8h*)(xrow + 32);
    v4f acc = {bias, bias, bias, bias};
    acc = __builtin_amdgcn_mfma_f32_16x16x32_f16(Am0, BL0, acc, 0, 0, 0);
    acc = __builtin_amdgcn_mfma_f32_16x16x32_f16(Am1, BL1, acc, 0, 0, 0);
    acc = __builtin_amdgcn_mfma_f32_16x16x32_f16(Ax0, BR0, acc, 0, 0, 0);
    acc = __builtin_amdgcn_mfma_f32_16x16x32_f16(Ax1, BR1, acc, 0, 0, 0);
#pragma unroll
    for (int r = 0; r < 4; ++r)
      st[(quad * 4 + r) * 68 + wid * 16 + mlo] = fmaxf(acc[r], 0.f);
  }
  __syncthreads();

  // ---- phase 3: output ----
  if (!LAYER2) {
    // coalesced fp16 store of the 16x64 tile: row = tid>>4, 4 cols per thread
    int r = tid >> 4;
    int c = (tid & 15) * 4;
    const float* ap = &st[r * 68 + c];
    v4u o;
    o.x = f2h(ap[0]); o.y = f2h(ap[1]); o.z = f2h(ap[2]); o.w = f2h(ap[3]);
    *(v4u*)(outh + (size_t)(node0 + r) * HDIM + c) = o;
  } else {
    // classifier: 16 threads/node, 2 hidden units each, shfl-tree reduce
    int nd = tid >> 4;
    int f = (tid & 15) * 2;
    float h0 = bc1[f], h1 = bc1[f + 1];
    const float* xr = &st[nd * 68];
#pragma unroll
    for (int k = 0; k < 64; ++k) {
      float xv = xr[k];
      h0 += xv * sW1[k * 32 + f];
      h1 += xv * sW1[k * 32 + f + 1];
    }
    h0 = fmaxf(h0, 0.f);
    h1 = fmaxf(h1, 0.f);
    float o0 = h0 * Wc2[f * 2 + 0] + h1 * Wc2[(f + 1) * 2 + 0];
    float o1 = h0 * Wc2[f * 2 + 1] + h1 * Wc2[(f + 1) * 2 + 1];
#pragma unroll
    for (int m = 8; m >= 1; m >>= 1) {
      o0 += __shfl_xor(o0, m);
      o1 += __shfl_xor(o1, m);
    }
    if ((tid & 15) == 0) {
      float2 ov;
      ov.x = o0 + bc2[0];
      ov.y = o1 + bc2[1];
      *(float2*)(dout + (size_t)(node0 + nd) * 2) = ov;
    }
  }
}

extern "C" void kernel_launch(void* const* d_in, const int* in_sizes, int n_in,
                              void* d_out, int out_size, void* d_ws, size_t ws_size,
                              hipStream_t stream) {
  const float* x_ind = (const float*)d_in[0];
  const float* x_com = (const float*)d_in[1];
  const float* x_tru = (const float*)d_in[2];
  const int*   ei    = (const int*)d_in[3];
  const float* W_ind = (const float*)d_in[4];
  const float* b_ind = (const float*)d_in[5];
  const float* W_com = (const float*)d_in[6];
  const float* b_com = (const float*)d_in[7];
  const float* W_tru = (const float*)d_in[8];
  const float* b_tru = (const float*)d_in[9];
  const float* W1l = (const float*)d_in[10];
  const float* W1r = (const float*)d_in[11];
  const float* b1  = (const float*)d_in[12];
  const float* W2l = (const float*)d_in[13];
  const float* W2r = (const float*)d_in[14];
  const float* b2  = (const float*)d_in[15];
  const float* Wc1 = (const float*)d_in[16];
  const float* bc1 = (const float*)d_in[17];
  const float* Wc2 = (const float*)d_in[18];
  const float* bc2 = (const float*)d_in[19];

  const int* srcp = ei;           // edge_index[0]
  const int* dstp = ei + NEDGE;   // edge_index[1]

  // workspace layout (~118 MB; previous rounds proved >=252 MB available)
  size_t fcount = (size_t)NTOT * HDIM;
  unsigned* packed = (unsigned*)d_ws;                     // edge staging (19.2 MB)
  unsigned short* xh0 = (unsigned short*)(packed + NEDGE);  // fp16 layer-0 features
  unsigned short* xh1 = xh0 + fcount;                       // fp16 layer-1 features
  int* eidx    = (int*)(xh1 + fcount);
  int* nodeoff = eidx + NEDGE;
  int* deg     = nodeoff + NTOT;
  int* chist   = deg + NTOT;
  int* cbase   = chist + NCB;
  int* ccur    = cbase + NCB;
  // 16B-aligned weight-fragment area (4 matrices x 4096 halfs = 32 KB)
  unsigned short* wfrag = (unsigned short*)((((size_t)(ccur + NCB)) + 15) & ~(size_t)15);
  size_t needed = (size_t)((char*)(wfrag + 4 * 4096) - (char*)d_ws) + 64;
  if (ws_size < needed) return;  // would corrupt; fail visibly instead

  (void)hipMemsetAsync(chist, 0, (size_t)NCB * sizeof(int), stream);

  // weight prep (fp16 + fragment swizzle), independent of everything else
  prep_weights_kernel<<<1, 256, 0, stream>>>(W1l, W1r, W2l, W2r, wfrag);

  // encoders (write fp16 xh0; independent of edge pipeline)
  encode_kernel<32><<<(N_IND + 255) / 256, 256, 0, stream>>>(x_ind, W_ind, b_ind, xh0, N_IND, 0);
  encode_kernel<48><<<(N_COM + 255) / 256, 256, 0, stream>>>(x_com, W_com, b_com, xh0, N_COM, N_IND);
  encode_kernel<24><<<(N_TRU + 255) / 256, 256, 0, stream>>>(x_tru, W_tru, b_tru, xh0, N_TRU, N_IND + N_COM);

  // coarse partition -> per-coarse-bucket counting sort -> node-grouped CSR
  coarse_hist_kernel<<<NCHUNKS, 256, 0, stream>>>(dstp, chist, NEDGE);
  coarse_scan_kernel<<<1, 512, 0, stream>>>(chist, cbase, ccur);
  coarse_scatter_kernel<<<NCHUNKS, 256, 0, stream>>>(srcp, dstp, ccur, packed, NEDGE);
  sort_coarse_kernel<<<NCB, 256, 0, stream>>>(packed, cbase, chist, eidx, nodeoff, deg);

  // SAGE layer 1 fused: aggregate -> LDS -> MFMA combine -> fp16 xh1
  agg_combine_kernel<false><<<NTILES, 256, 0, stream>>>(
      xh0, nodeoff, deg, eidx, wfrag, b1, xh1, nullptr, nullptr, nullptr, nullptr, nullptr);

  // SAGE layer 2 fused: aggregate -> LDS -> MFMA combine -> classifier -> d_out
  agg_combine_kernel<true><<<NTILES, 256, 0, stream>>>(
      xh1, nodeoff, deg, eidx, wfrag + 2 * 4096, b2, nullptr, Wc1, bc1, Wc2, bc2,
      (float*)d_out);
}